// Round 12
// baseline (452.514 us; speedup 1.0000x reference)
//
#include <hip/hip_runtime.h>

typedef unsigned short u16;
typedef __attribute__((ext_vector_type(8))) short bf8_t;   // 8 bf16 (4 VGPR) MFMA A/B frag
typedef __attribute__((ext_vector_type(4))) float f4_t;    // MFMA C/D frag

__device__ __forceinline__ float bf2f(u16 v) {
    union { unsigned u; float f; } c; c.u = ((unsigned)v) << 16; return c.f;
}
__device__ __forceinline__ u16 f2bf(float f) {  // RNE f32 -> bf16
    union { float f; unsigned u; } c; c.f = f;
    unsigned r = 0x7FFFu + ((c.u >> 16) & 1u);
    return (u16)((c.u + r) >> 16);
}

#define B_   4
#define N_   2048
#define INC  256
#define H_   8
#define ROWS 8192

// canonical (bf16) segment offsets within cvt, u16 units. Weights stored TRANSPOSED: Bt[n][k].
#define SEG_X     0
#define SEG_LN1G  2097152
#define SEG_LN1B  2097408
#define SEG_WQKV  2097664
#define SEG_BQKV  2753024
#define SEG_WM    2755584
#define SEG_BM    3279872
#define SEG_LN2G  3280128
#define SEG_LN2B  3280384
#define SEG_W1    3280640
#define SEG_B1    3542784
#define SEG_W2    3543808
#define SEG_B2    3805952
#define SEG_TOT   3806208

// ---------------- dtype sniffer ----------------
__global__ __launch_bounds__(256) void sniff_k(const u16* __restrict__ x, int* __restrict__ flag) {
    __shared__ int s;
    int t = threadIdx.x;
    if (t == 0) s = 0;
    __syncthreads();
    int bad = 0;
    for (int i = t; i < 8192; i += 256) {
        float v = bf2f(x[i]);
        if (!(fabsf(v) < 1e10f)) bad = 1;
    }
    if (bad) atomicOr(&s, 1);
    __syncthreads();
    if (t == 0) *flag = s;   // 1 => inputs fp32, 0 => bf16
}

// ---------------- canonicalize inputs to bf16; weights transposed ----------------
__global__ __launch_bounds__(256) void conv_k(
    const void* p0, const void* p1, const void* p2, const void* p3, const void* p4,
    const void* p5, const void* p6, const void* p7, const void* p8, const void* p9,
    const void* p10, const void* p11, const void* p12,
    const int* __restrict__ flag, u16* __restrict__ dst)
{
    int i = blockIdx.x * 256 + threadIdx.x;
    if (i >= SEG_TOT) return;
    const void* p; int j;
    if      (i < SEG_LN1G) { p = p0;  j = i; }
    else if (i < SEG_LN1B) { p = p1;  j = i - SEG_LN1G; }
    else if (i < SEG_WQKV) { p = p2;  j = i - SEG_LN1B; }
    else if (i < SEG_BQKV) { p = p3;  int ii = i - SEG_WQKV;          // WqkvT[n][k]: n<2560,k<256
                             int n = ii >> 8, k = ii & 255; j = k * 2560 + n; }
    else if (i < SEG_WM)   { p = p4;  j = i - SEG_BQKV; }
    else if (i < SEG_BM)   { p = p5;  int ii = i - SEG_WM;            // WmT[n][k]: n<256,k<2048
                             int n = ii >> 11, k = ii & 2047; j = k * 256 + n; }
    else if (i < SEG_LN2G) { p = p6;  j = i - SEG_BM; }
    else if (i < SEG_LN2B) { p = p7;  j = i - SEG_LN2G; }
    else if (i < SEG_W1)   { p = p8;  j = i - SEG_LN2B; }
    else if (i < SEG_B1)   { p = p9;  int ii = i - SEG_W1;            // W1T[n][k]: n<1024,k<256
                             int n = ii >> 8, k = ii & 255; j = k * 1024 + n; }
    else if (i < SEG_W2)   { p = p10; j = i - SEG_B1; }
    else if (i < SEG_B2)   { p = p11; int ii = i - SEG_W2;            // W2T[n][k]: n<256,k<1024
                             int n = ii >> 10, k = ii & 1023; j = k * 256 + n; }
    else                   { p = p12; j = i - SEG_B2; }
    dst[i] = (*flag) ? f2bf(((const float*)p)[j]) : ((const u16*)p)[j];
}

// ---------------- LayerNorm, one wave per row (no barriers), 4 rows/block ----------------
template<bool BF16IN>
__global__ __launch_bounds__(256) void ln_k(const void* __restrict__ xp,
        const u16* __restrict__ g, const u16* __restrict__ b, u16* __restrict__ y)
{
    int row  = blockIdx.x * 4 + (threadIdx.x >> 6);
    int lane = threadIdx.x & 63;
    int c0   = lane * 4;
    float v[4];
    if (BF16IN) {
        ushort4 u = *(const ushort4*)((const u16*)xp + (size_t)row * INC + c0);
        v[0] = bf2f(u.x); v[1] = bf2f(u.y); v[2] = bf2f(u.z); v[3] = bf2f(u.w);
    } else {
        float4 f = *(const float4*)((const float*)xp + (size_t)row * INC + c0);
        v[0] = f.x; v[1] = f.y; v[2] = f.z; v[3] = f.w;
    }
    float s = v[0] + v[1] + v[2] + v[3];
    float s2 = v[0]*v[0] + v[1]*v[1] + v[2]*v[2] + v[3]*v[3];
    #pragma unroll
    for (int d = 1; d < 64; d <<= 1) {
        s  += __shfl_xor(s,  d, 64);
        s2 += __shfl_xor(s2, d, 64);
    }
    float mean = s * (1.0f / INC);
    float var  = s2 * (1.0f / INC) - mean * mean;
    float inv  = rsqrtf(var + 1e-5f);
    ushort4 gو = *(const ushort4*)(g + c0);
    ushort4 bو = *(const ushort4*)(b + c0);
    ushort4 o;
    o.x = f2bf((v[0] - mean) * inv * bf2f(gو.x) + bf2f(bو.x));
    o.y = f2bf((v[1] - mean) * inv * bf2f(gو.y) + bf2f(bو.y));
    o.z = f2bf((v[2] - mean) * inv * bf2f(gو.z) + bf2f(bو.z));
    o.w = f2bf((v[3] - mean) * inv * bf2f(gو.w) + bf2f(bو.w));
    *(ushort4*)(y + (size_t)row * INC + c0) = o;
}

// ---------------- per-head max key L2-norm ----------------
__global__ __launch_bounds__(256) void maxk_k(const u16* __restrict__ kh, float* __restrict__ mk) {
    int bh = blockIdx.x, t = threadIdx.x;
    const u16* Kp = kh + (size_t)bh * 2048 * 32;
    float mx = 0.f;
    for (int n = t; n < 2048; n += 256) {
        const u16* kr = Kp + (size_t)n * 32;
        float s = 0.f;
        #pragma unroll
        for (int c = 0; c < 32; c += 4) {
            ushort4 v = *(const ushort4*)(kr + c);
            float f0 = bf2f(v.x), f1 = bf2f(v.y), f2 = bf2f(v.z), f3 = bf2f(v.w);
            s += f0 * f0 + f1 * f1 + f2 * f2 + f3 * f3;
        }
        mx = fmaxf(mx, s);
    }
    #pragma unroll
    for (int d = 1; d < 64; d <<= 1) mx = fmaxf(mx, __shfl_xor(mx, d, 64));
    __shared__ float red[4];
    if ((t & 63) == 0) red[t >> 6] = mx;
    __syncthreads();
    if (t == 0) mk[bh] = sqrtf(fmaxf(fmaxf(red[0], red[1]), fmaxf(red[2], red[3])));
}

enum { EP_QKV = 0, EP_MERGE = 1, EP_GELU = 2, EP_FFN2 = 3 };

// ---------------- big-tile GEMM (QKV / GELU): wave 64x64, block 256x64, 2:1 MFMA:load ----
template<int MODE>
__global__ __launch_bounds__(256) void gemm_big(
    const u16* __restrict__ A, const u16* __restrict__ Bt,
    const u16* __restrict__ bias, void* __restrict__ outp,
    u16* __restrict__ qh, u16* __restrict__ kh, u16* __restrict__ vh,
    int N, int K)
{
    const int t = threadIdx.x;
    const int w = t >> 6, lane = t & 63;
    const int l15 = lane & 15, quad = lane >> 4;
    const int col0 = blockIdx.x * 64;
    const int row0 = blockIdx.y * 256;
    const int mrow = row0 + w * 64;

    const u16* Ap = A  + (size_t)(mrow + l15) * K + quad * 8;
    const u16* Bp = Bt + (size_t)(col0 + l15) * K + quad * 8;

    f4_t acc[4][4];
    #pragma unroll
    for (int mi = 0; mi < 4; ++mi)
        #pragma unroll
        for (int ni = 0; ni < 4; ++ni)
            acc[mi][ni] = (f4_t){0.f, 0.f, 0.f, 0.f};

    for (int k0 = 0; k0 < K; k0 += 32) {
        bf8_t a[4], bb[4];
        #pragma unroll
        for (int mi = 0; mi < 4; ++mi)
            a[mi] = *(const bf8_t*)(Ap + (size_t)mi * 16 * K + k0);
        #pragma unroll
        for (int ni = 0; ni < 4; ++ni)
            bb[ni] = *(const bf8_t*)(Bp + (size_t)ni * 16 * K + k0);
        #pragma unroll
        for (int ni = 0; ni < 4; ++ni)
            #pragma unroll
            for (int mi = 0; mi < 4; ++mi)
                acc[mi][ni] = __builtin_amdgcn_mfma_f32_16x16x32_bf16(
                    a[mi], bb[ni], acc[mi][ni], 0, 0, 0);
    }

    if (MODE == EP_QKV) {
        if (col0 >= 512) {
            // V: transpose 256 tokens x 64 chans through LDS -> vhT[vchan][token]
            __shared__ u16 Ts[64][268];
            #pragma unroll
            for (int mi = 0; mi < 4; ++mi)
                #pragma unroll
                for (int ni = 0; ni < 4; ++ni) {
                    float bz = bf2f(bias[col0 + ni * 16 + l15]);
                    #pragma unroll
                    for (int r = 0; r < 4; ++r)
                        Ts[ni * 16 + l15][w * 64 + mi * 16 + quad * 4 + r] =
                            f2bf(acc[mi][ni][r] + bz);
                }
            __syncthreads();
            int vcg = col0 - 512;
            int hh  = vcg >> 8;
            int bb2 = row0 >> 11, nb = row0 & 2047;
            int cl  = t >> 2, seg = t & 3;
            u16* dp = vh + ((size_t)(bb2 * 8 + hh) * 256 + (vcg & 255) + cl) * 2048
                         + nb + seg * 64;
            #pragma unroll
            for (int ii = 0; ii < 64; ii += 4)
                *(ushort4*)(dp + ii) = *(const ushort4*)&Ts[cl][seg * 64 + ii];
        } else {
            #pragma unroll
            for (int mi = 0; mi < 4; ++mi)
                #pragma unroll
                for (int r = 0; r < 4; ++r) {
                    int rg = mrow + mi * 16 + quad * 4 + r;
                    int bb2 = rg >> 11, n = rg & 2047;
                    #pragma unroll
                    for (int ni = 0; ni < 4; ++ni) {
                        int col = col0 + ni * 16 + l15;
                        float v = acc[mi][ni][r] + bf2f(bias[col]);
                        if (col < 256)
                            qh[(((size_t)(bb2 * 8 + (col >> 5))) * 2048 + n) * 32 + (col & 31)] = f2bf(v);
                        else {
                            int c2 = col - 256;
                            kh[(((size_t)(bb2 * 8 + (c2 >> 5))) * 2048 + n) * 32 + (c2 & 31)] = f2bf(v);
                        }
                    }
                }
        }
    } else {   // EP_GELU: exact gelu -> bf16 hidden
        float bz[4];
        #pragma unroll
        for (int ni = 0; ni < 4; ++ni) bz[ni] = bf2f(bias[col0 + ni * 16 + l15]);
        #pragma unroll
        for (int mi = 0; mi < 4; ++mi)
            #pragma unroll
            for (int r = 0; r < 4; ++r) {
                int rg = mrow + mi * 16 + quad * 4 + r;
                size_t base = (size_t)rg * N + col0 + l15;
                #pragma unroll
                for (int ni = 0; ni < 4; ++ni) {
                    float v = acc[mi][ni][r] + bz[ni];
                    v = 0.5f * v * (1.0f + erff(v * 0.70710678118654752f));
                    ((u16*)outp)[base + ni * 16] = f2bf(v);
                }
            }
    }
}

// ---------------- MFMA GEMM (MERGE / FFN2): block 128x64 ----------------
template<int MODE>
__global__ __launch_bounds__(256) void gemm_mfma(
    const u16* __restrict__ A, const u16* __restrict__ Bt,
    const u16* __restrict__ bias, const void* __restrict__ res,
    void* __restrict__ outp, int N, int K)
{
    const int t = threadIdx.x;
    const int w = t >> 6, lane = t & 63;
    const int l15 = lane & 15, quad = lane >> 4;
    const int col0 = blockIdx.x * 64;
    const int row0 = blockIdx.y * 128;
    const int mrow = row0 + w * 32;

    const u16* Ap = A  + (size_t)(mrow + l15) * K + quad * 8;
    const u16* Bp = Bt + (size_t)(col0 + l15) * K + quad * 8;

    f4_t acc[2][4];
    #pragma unroll
    for (int mi = 0; mi < 2; ++mi)
        #pragma unroll
        for (int ni = 0; ni < 4; ++ni)
            acc[mi][ni] = (f4_t){0.f, 0.f, 0.f, 0.f};

    for (int k0 = 0; k0 < K; k0 += 64) {
        bf8_t a[2][2], bb[4][2];
        #pragma unroll
        for (int kc = 0; kc < 2; ++kc) {
            #pragma unroll
            for (int mi = 0; mi < 2; ++mi)
                a[mi][kc] = *(const bf8_t*)(Ap + (size_t)mi * 16 * K + k0 + kc * 32);
            #pragma unroll
            for (int ni = 0; ni < 4; ++ni)
                bb[ni][kc] = *(const bf8_t*)(Bp + (size_t)ni * 16 * K + k0 + kc * 32);
        }
        #pragma unroll
        for (int kc = 0; kc < 2; ++kc)
            #pragma unroll
            for (int ni = 0; ni < 4; ++ni)
                #pragma unroll
                for (int mi = 0; mi < 2; ++mi)
                    acc[mi][ni] = __builtin_amdgcn_mfma_f32_16x16x32_bf16(
                        a[mi][kc], bb[ni][kc], acc[mi][ni], 0, 0, 0);
    }

    float bz[4];
    #pragma unroll
    for (int ni = 0; ni < 4; ++ni) bz[ni] = bf2f(bias[col0 + ni * 16 + l15]);
    #pragma unroll
    for (int mi = 0; mi < 2; ++mi)
        #pragma unroll
        for (int r = 0; r < 4; ++r) {
            int rg = mrow + mi * 16 + quad * 4 + r;
            size_t base = (size_t)rg * N + col0 + l15;
            if (MODE == EP_MERGE) {          // + bm + x (bf16) -> f32 x2
                const u16* R = (const u16*)res;
                #pragma unroll
                for (int ni = 0; ni < 4; ++ni)
                    ((float*)outp)[base + ni * 16] =
                        acc[mi][ni][r] + bz[ni] + bf2f(R[base + ni * 16]);
            } else {                          // EP_FFN2: + x2 (f32) -> fp32 d_out
                const float* R = (const float*)res;
                #pragma unroll
                for (int ni = 0; ni < 4; ++ni)
                    ((float*)outp)[base + ni * 16] =
                        acc[mi][ni][r] + bz[ni] + R[base + ni * 16];
            }
        }
}

// ---------------- MFMA flash attention, single-pass, norm-bound max, S^T form ----------------
__global__ __launch_bounds__(256, 4) void attn_k(
    const u16* __restrict__ qh, const u16* __restrict__ kh,
    const u16* __restrict__ vhT, const float* __restrict__ maxk,
    u16* __restrict__ ao)
{
    const int t = threadIdx.x;
    const int w = t >> 6, lane = t & 63;
    const int l15 = lane & 15, quad = lane >> 4;
    const int id = blockIdx.x;
    const int qt = (id >> 3) & 31;
    const int bh = (id >> 8) * 8 + (id & 7);   // id%8 = XCD affinity per (b,h)
    const int b  = bh >> 3, h = bh & 7;
    const int n0 = qt * 64;
    const float SCALE = 0.17677669529663687f;  // 1/sqrt(32)

    const u16* Q  = qh  + (size_t)bh * 2048 * 32;
    const u16* Kp = kh  + (size_t)bh * 2048 * 32;
    const u16* Vt = vhT + (size_t)bh * 256 * 2048;   // [vchan][key]

    __shared__ __align__(16) u16 Pb[2][64][136];     // [buf][q row][key 0..127 +pad]
    __shared__ __align__(16) float lds_l[64];

    const bf8_t qf = *(const bf8_t*)(Q + (size_t)(n0 + 16 * w + l15) * 32 + quad * 8);
    const f4_t zf = {0.f, 0.f, 0.f, 0.f};

    float q2 = 0.f;
    #pragma unroll
    for (int i = 0; i < 8; ++i) { float qv = bf2f((u16)qf[i]); q2 += qv * qv; }
    q2 += __shfl_xor(q2, 16, 64);
    q2 += __shfl_xor(q2, 32, 64);
    const float mrow = SCALE * sqrtf(q2) * maxk[bh];

    f4_t acc[4][4];
    #pragma unroll
    for (int i = 0; i < 4; ++i)
        #pragma unroll
        for (int j = 0; j < 4; ++j)
            acc[i][j] = (f4_t){0.f, 0.f, 0.f, 0.f};
    float lsum = 0.f;

    int bufi = 0;
    for (int kt = 0; kt < 2048; kt += 128, bufi ^= 1) {
        #pragma unroll
        for (int jt = 0; jt < 8; ++jt) {
            bf8_t kf = *(const bf8_t*)(Kp + (size_t)(kt + jt * 16 + l15) * 32 + quad * 8);
            f4_t s = __builtin_amdgcn_mfma_f32_16x16x32_bf16(kf, qf, zf, 0, 0, 0);
            float p0 = __expf(fmaf(s[0], SCALE, -mrow));
            float p1 = __expf(fmaf(s[1], SCALE, -mrow));
            float p2 = __expf(fmaf(s[2], SCALE, -mrow));
            float p3 = __expf(fmaf(s[3], SCALE, -mrow));
            lsum += (p0 + p1) + (p2 + p3);
            ushort4 pk;
            pk.x = f2bf(p0); pk.y = f2bf(p1); pk.z = f2bf(p2); pk.w = f2bf(p3);
            *(ushort4*)&Pb[bufi][16 * w + l15][jt * 16 + quad * 4] = pk;
        }
        __syncthreads();
        #pragma unroll
        for (int kc = 0; kc < 4; ++kc) {
            bf8_t af[4];
            #pragma unroll
            for (int mt = 0; mt < 4; ++mt)
                af[mt] = *(const bf8_t*)&Pb[bufi][mt * 16 + l15][kc * 32 + quad * 8];
            #pragma unroll
            for (int nt = 0; nt < 4; ++nt) {
                bf8_t vf = *(const bf8_t*)(Vt + (size_t)(64 * w + nt * 16 + l15) * 2048
                                           + kt + kc * 32 + quad * 8);
                #pragma unroll
                for (int mt = 0; mt < 4; ++mt)
                    acc[mt][nt] = __builtin_amdgcn_mfma_f32_16x16x32_bf16(
                        af[mt], vf, acc[mt][nt], 0, 0, 0);
            }
        }
    }

    lsum += __shfl_xor(lsum, 16, 64);
    lsum += __shfl_xor(lsum, 32, 64);
    if (lane < 16) lds_l[16 * w + l15] = lsum;
    __syncthreads();
    #pragma unroll
    for (int mt = 0; mt < 4; ++mt) {
        f4_t lv = *(const f4_t*)&lds_l[mt * 16 + quad * 4];
        #pragma unroll
        for (int r = 0; r < 4; ++r) {
            float inv = 1.0f / lv[r];
            size_t rowbase = ((size_t)(b * 2048 + n0 + mt * 16 + quad * 4 + r)) * 2048
                             + h * 256 + 64 * w;
            #pragma unroll
            for (int nt = 0; nt < 4; ++nt)
                ao[rowbase + nt * 16 + l15] = f2bf(acc[mt][nt][r] * inv);
        }
    }
}

extern "C" void kernel_launch(void* const* d_in, const int* in_sizes, int n_in,
                              void* d_out, int out_size, void* d_ws, size_t ws_size,
                              hipStream_t stream)
{
    u16* wsu = (u16*)d_ws;
    int* flag = (int*)d_ws;
    float* mk = (float*)(wsu + 64);              // 32 f32

    // workspace layout (u16 units), ~95.7 MB (known-safe)
    const size_t CVT0 = 128;
    const size_t Y0   = CVT0 + SEG_TOT;          // y bf16 [8192,256]
    const size_t QH0  = Y0  + 2097152;
    const size_t KH0  = QH0 + 2097152;
    const size_t VT0  = KH0 + 2097152;           // vhT bf16 [B*H*256][2048]
    const size_t AO0  = VT0 + 16777216;          // ao bf16 [8192][2048]
    const size_t X20  = AO0 + 16777216;          // x2 f32 [8192,256]
    // hbb bf16 [8192,1024] aliases AO0 (ao dead after merge GEMM)

    u16* cvt = wsu + CVT0;
    u16* y   = wsu + Y0;
    u16* qh  = wsu + QH0;
    u16* kh  = wsu + KH0;
    u16* vhT = wsu + VT0;
    u16* ao  = wsu + AO0;
    float* x2 = (float*)(wsu + X20);
    u16* hbb  = wsu + AO0;

    const u16* xc   = cvt + SEG_X;
    const u16* ln1g = cvt + SEG_LN1G;
    const u16* ln1b = cvt + SEG_LN1B;
    const u16* Wqkv = cvt + SEG_WQKV;   // transposed [2560][256]
    const u16* bqkv = cvt + SEG_BQKV;
    const u16* Wm   = cvt + SEG_WM;     // transposed [256][2048]
    const u16* bm   = cvt + SEG_BM;
    const u16* ln2g = cvt + SEG_LN2G;
    const u16* ln2b = cvt + SEG_LN2B;
    const u16* W1   = cvt + SEG_W1;     // transposed [1024][256]
    const u16* b1   = cvt + SEG_B1;
    const u16* W2   = cvt + SEG_W2;     // transposed [256][1024]
    const u16* b2   = cvt + SEG_B2;

    sniff_k<<<1, 256, 0, stream>>>((const u16*)d_in[0], flag);
    conv_k<<<SEG_TOT / 256, 256, 0, stream>>>(
        d_in[0], d_in[1], d_in[2], d_in[3], d_in[4], d_in[5], d_in[6],
        d_in[7], d_in[8], d_in[9], d_in[10], d_in[11], d_in[12], flag, cvt);

    ln_k<true><<<ROWS / 4, 256, 0, stream>>>(xc, ln1g, ln1b, y);
    gemm_big<EP_QKV><<<dim3(2560 / 64, ROWS / 256), 256, 0, stream>>>(
        y, Wqkv, bqkv, nullptr, qh, kh, vhT, 2560, 256);
    maxk_k<<<32, 256, 0, stream>>>(kh, mk);
    attn_k<<<1024, 256, 0, stream>>>(qh, kh, vhT, mk, ao);
    gemm_mfma<EP_MERGE><<<dim3(256 / 64, ROWS / 128), 256, 0, stream>>>(
        ao, Wm, bm, xc, x2, 256, 2048);
    ln_k<false><<<ROWS / 4, 256, 0, stream>>>(x2, ln2g, ln2b, y);
    gemm_big<EP_GELU><<<dim3(1024 / 64, ROWS / 256), 256, 0, stream>>>(
        y, W1, b1, hbb, nullptr, nullptr, nullptr, 1024, 256);
    gemm_mfma<EP_FFN2><<<dim3(256 / 64, ROWS / 128), 256, 0, stream>>>(
        hbb, W2, b2, x2, d_out, 256, 1024);
}

// Round 13
// 429.744 us; speedup vs baseline: 1.0530x; 1.0530x over previous
//
#include <hip/hip_runtime.h>

typedef unsigned short u16;
typedef __attribute__((ext_vector_type(8))) short bf8_t;   // 8 bf16 (4 VGPR) MFMA A/B frag
typedef __attribute__((ext_vector_type(4))) float f4_t;    // MFMA C/D frag

__device__ __forceinline__ float bf2f(u16 v) {
    union { unsigned u; float f; } c; c.u = ((unsigned)v) << 16; return c.f;
}
__device__ __forceinline__ u16 f2bf(float f) {  // RNE f32 -> bf16
    union { float f; unsigned u; } c; c.f = f;
    unsigned r = 0x7FFFu + ((c.u >> 16) & 1u);
    return (u16)((c.u + r) >> 16);
}

#define B_   4
#define N_   2048
#define INC  256
#define H_   8
#define ROWS 8192

// canonical (bf16) segment offsets within cvt, u16 units. Weights stored TRANSPOSED: Bt[n][k].
#define SEG_X     0
#define SEG_LN1G  2097152
#define SEG_LN1B  2097408
#define SEG_WQKV  2097664
#define SEG_BQKV  2753024
#define SEG_WM    2755584
#define SEG_BM    3279872
#define SEG_LN2G  3280128
#define SEG_LN2B  3280384
#define SEG_W1    3280640
#define SEG_B1    3542784
#define SEG_W2    3543808
#define SEG_B2    3805952
#define SEG_TOT   3806208

// ---------------- dtype sniffer ----------------
__global__ __launch_bounds__(256) void sniff_k(const u16* __restrict__ x, int* __restrict__ flag) {
    __shared__ int s;
    int t = threadIdx.x;
    if (t == 0) s = 0;
    __syncthreads();
    int bad = 0;
    for (int i = t; i < 8192; i += 256) {
        float v = bf2f(x[i]);
        if (!(fabsf(v) < 1e10f)) bad = 1;
    }
    if (bad) atomicOr(&s, 1);
    __syncthreads();
    if (t == 0) *flag = s;   // 1 => inputs fp32, 0 => bf16
}

// ---------------- canonicalize inputs to bf16; weights transposed ----------------
__global__ __launch_bounds__(256) void conv_k(
    const void* p0, const void* p1, const void* p2, const void* p3, const void* p4,
    const void* p5, const void* p6, const void* p7, const void* p8, const void* p9,
    const void* p10, const void* p11, const void* p12,
    const int* __restrict__ flag, u16* __restrict__ dst)
{
    int i = blockIdx.x * 256 + threadIdx.x;
    if (i >= SEG_TOT) return;
    const void* p; int j;
    if      (i < SEG_LN1G) { p = p0;  j = i; }
    else if (i < SEG_LN1B) { p = p1;  j = i - SEG_LN1G; }
    else if (i < SEG_WQKV) { p = p2;  j = i - SEG_LN1B; }
    else if (i < SEG_BQKV) { p = p3;  int ii = i - SEG_WQKV;          // WqkvT[n][k]: n<2560,k<256
                             int n = ii >> 8, k = ii & 255; j = k * 2560 + n; }
    else if (i < SEG_WM)   { p = p4;  j = i - SEG_BQKV; }
    else if (i < SEG_BM)   { p = p5;  int ii = i - SEG_WM;            // WmT[n][k]: n<256,k<2048
                             int n = ii >> 11, k = ii & 2047; j = k * 256 + n; }
    else if (i < SEG_LN2G) { p = p6;  j = i - SEG_BM; }
    else if (i < SEG_LN2B) { p = p7;  j = i - SEG_LN2G; }
    else if (i < SEG_W1)   { p = p8;  j = i - SEG_LN2B; }
    else if (i < SEG_B1)   { p = p9;  int ii = i - SEG_W1;            // W1T[n][k]: n<1024,k<256
                             int n = ii >> 8, k = ii & 255; j = k * 1024 + n; }
    else if (i < SEG_W2)   { p = p10; j = i - SEG_B1; }
    else if (i < SEG_B2)   { p = p11; int ii = i - SEG_W2;            // W2T[n][k]: n<256,k<1024
                             int n = ii >> 10, k = ii & 1023; j = k * 256 + n; }
    else                   { p = p12; j = i - SEG_B2; }
    dst[i] = (*flag) ? f2bf(((const float*)p)[j]) : ((const u16*)p)[j];
}

// ---------------- LayerNorm, one wave per row (no barriers), 4 rows/block ----------------
template<bool BF16IN>
__global__ __launch_bounds__(256) void ln_k(const void* __restrict__ xp,
        const u16* __restrict__ g, const u16* __restrict__ b, u16* __restrict__ y)
{
    int row  = blockIdx.x * 4 + (threadIdx.x >> 6);
    int lane = threadIdx.x & 63;
    int c0   = lane * 4;
    float v[4];
    if (BF16IN) {
        ushort4 u = *(const ushort4*)((const u16*)xp + (size_t)row * INC + c0);
        v[0] = bf2f(u.x); v[1] = bf2f(u.y); v[2] = bf2f(u.z); v[3] = bf2f(u.w);
    } else {
        float4 f = *(const float4*)((const float*)xp + (size_t)row * INC + c0);
        v[0] = f.x; v[1] = f.y; v[2] = f.z; v[3] = f.w;
    }
    float s = v[0] + v[1] + v[2] + v[3];
    float s2 = v[0]*v[0] + v[1]*v[1] + v[2]*v[2] + v[3]*v[3];
    #pragma unroll
    for (int d = 1; d < 64; d <<= 1) {
        s  += __shfl_xor(s,  d, 64);
        s2 += __shfl_xor(s2, d, 64);
    }
    float mean = s * (1.0f / INC);
    float var  = s2 * (1.0f / INC) - mean * mean;
    float inv  = rsqrtf(var + 1e-5f);
    ushort4 gv = *(const ushort4*)(g + c0);
    ushort4 bv = *(const ushort4*)(b + c0);
    ushort4 o;
    o.x = f2bf((v[0] - mean) * inv * bf2f(gv.x) + bf2f(bv.x));
    o.y = f2bf((v[1] - mean) * inv * bf2f(gv.y) + bf2f(bv.y));
    o.z = f2bf((v[2] - mean) * inv * bf2f(gv.z) + bf2f(bv.z));
    o.w = f2bf((v[3] - mean) * inv * bf2f(gv.w) + bf2f(bv.w));
    *(ushort4*)(y + (size_t)row * INC + c0) = o;
}

// ---------------- per-head max key L2-norm ----------------
__global__ __launch_bounds__(256) void maxk_k(const u16* __restrict__ kh, float* __restrict__ mk) {
    int bh = blockIdx.x, t = threadIdx.x;
    const u16* Kp = kh + (size_t)bh * 2048 * 32;
    float mx = 0.f;
    for (int n = t; n < 2048; n += 256) {
        const u16* kr = Kp + (size_t)n * 32;
        float s = 0.f;
        #pragma unroll
        for (int c = 0; c < 32; c += 4) {
            ushort4 v = *(const ushort4*)(kr + c);
            float f0 = bf2f(v.x), f1 = bf2f(v.y), f2 = bf2f(v.z), f3 = bf2f(v.w);
            s += f0 * f0 + f1 * f1 + f2 * f2 + f3 * f3;
        }
        mx = fmaxf(mx, s);
    }
    #pragma unroll
    for (int d = 1; d < 64; d <<= 1) mx = fmaxf(mx, __shfl_xor(mx, d, 64));
    __shared__ float red[4];
    if ((t & 63) == 0) red[t >> 6] = mx;
    __syncthreads();
    if (t == 0) mk[bh] = sqrtf(fmaxf(fmaxf(red[0], red[1]), fmaxf(red[2], red[3])));
}

enum { EP_QKV = 0, EP_MERGE = 1, EP_GELU = 2, EP_FFN2 = 3 };

// ---------------- big-tile GEMM (QKV / GELU): wave 64x64, block 256x64, 2:1 MFMA:load ----
template<int MODE>
__global__ __launch_bounds__(256) void gemm_big(
    const u16* __restrict__ A, const u16* __restrict__ Bt,
    const u16* __restrict__ bias, void* __restrict__ outp,
    u16* __restrict__ qh, u16* __restrict__ kh, u16* __restrict__ vh,
    int N, int K)
{
    const int t = threadIdx.x;
    const int w = t >> 6, lane = t & 63;
    const int l15 = lane & 15, quad = lane >> 4;
    const int col0 = blockIdx.x * 64;
    const int row0 = blockIdx.y * 256;
    const int mrow = row0 + w * 64;

    const u16* Ap = A  + (size_t)(mrow + l15) * K + quad * 8;
    const u16* Bp = Bt + (size_t)(col0 + l15) * K + quad * 8;

    f4_t acc[4][4];
    #pragma unroll
    for (int mi = 0; mi < 4; ++mi)
        #pragma unroll
        for (int ni = 0; ni < 4; ++ni)
            acc[mi][ni] = (f4_t){0.f, 0.f, 0.f, 0.f};

    for (int k0 = 0; k0 < K; k0 += 32) {
        bf8_t a[4], bb[4];
        #pragma unroll
        for (int mi = 0; mi < 4; ++mi)
            a[mi] = *(const bf8_t*)(Ap + (size_t)mi * 16 * K + k0);
        #pragma unroll
        for (int ni = 0; ni < 4; ++ni)
            bb[ni] = *(const bf8_t*)(Bp + (size_t)ni * 16 * K + k0);
        #pragma unroll
        for (int ni = 0; ni < 4; ++ni)
            #pragma unroll
            for (int mi = 0; mi < 4; ++mi)
                acc[mi][ni] = __builtin_amdgcn_mfma_f32_16x16x32_bf16(
                    a[mi], bb[ni], acc[mi][ni], 0, 0, 0);
    }

    if (MODE == EP_QKV) {
        if (col0 >= 512) {
            // V: transpose 256 tokens x 64 chans through LDS -> vhT[vchan][token]
            __shared__ u16 Ts[64][268];
            #pragma unroll
            for (int mi = 0; mi < 4; ++mi)
                #pragma unroll
                for (int ni = 0; ni < 4; ++ni) {
                    float bz = bf2f(bias[col0 + ni * 16 + l15]);
                    #pragma unroll
                    for (int r = 0; r < 4; ++r)
                        Ts[ni * 16 + l15][w * 64 + mi * 16 + quad * 4 + r] =
                            f2bf(acc[mi][ni][r] + bz);
                }
            __syncthreads();
            int vcg = col0 - 512;
            int hh  = vcg >> 8;
            int bb2 = row0 >> 11, nb = row0 & 2047;
            int cl  = t >> 2, seg = t & 3;
            u16* dp = vh + ((size_t)(bb2 * 8 + hh) * 256 + (vcg & 255) + cl) * 2048
                         + nb + seg * 64;
            #pragma unroll
            for (int ii = 0; ii < 64; ii += 4)
                *(ushort4*)(dp + ii) = *(const ushort4*)&Ts[cl][seg * 64 + ii];
        } else {
            #pragma unroll
            for (int mi = 0; mi < 4; ++mi)
                #pragma unroll
                for (int r = 0; r < 4; ++r) {
                    int rg = mrow + mi * 16 + quad * 4 + r;
                    int bb2 = rg >> 11, n = rg & 2047;
                    #pragma unroll
                    for (int ni = 0; ni < 4; ++ni) {
                        int col = col0 + ni * 16 + l15;
                        float v = acc[mi][ni][r] + bf2f(bias[col]);
                        if (col < 256)
                            qh[(((size_t)(bb2 * 8 + (col >> 5))) * 2048 + n) * 32 + (col & 31)] = f2bf(v);
                        else {
                            int c2 = col - 256;
                            kh[(((size_t)(bb2 * 8 + (c2 >> 5))) * 2048 + n) * 32 + (c2 & 31)] = f2bf(v);
                        }
                    }
                }
        }
    } else {   // EP_GELU: exact gelu -> bf16 hidden
        float bz[4];
        #pragma unroll
        for (int ni = 0; ni < 4; ++ni) bz[ni] = bf2f(bias[col0 + ni * 16 + l15]);
        #pragma unroll
        for (int mi = 0; mi < 4; ++mi)
            #pragma unroll
            for (int r = 0; r < 4; ++r) {
                int rg = mrow + mi * 16 + quad * 4 + r;
                size_t base = (size_t)rg * N + col0 + l15;
                #pragma unroll
                for (int ni = 0; ni < 4; ++ni) {
                    float v = acc[mi][ni][r] + bz[ni];
                    v = 0.5f * v * (1.0f + erff(v * 0.70710678118654752f));
                    ((u16*)outp)[base + ni * 16] = f2bf(v);
                }
            }
    }
}

// ---------------- MFMA GEMM (MERGE / FFN2): block 128x64 ----------------
template<int MODE>
__global__ __launch_bounds__(256) void gemm_mfma(
    const u16* __restrict__ A, const u16* __restrict__ Bt,
    const u16* __restrict__ bias, const void* __restrict__ res,
    void* __restrict__ outp, int N, int K)
{
    const int t = threadIdx.x;
    const int w = t >> 6, lane = t & 63;
    const int l15 = lane & 15, quad = lane >> 4;
    const int col0 = blockIdx.x * 64;
    const int row0 = blockIdx.y * 128;
    const int mrow = row0 + w * 32;

    const u16* Ap = A  + (size_t)(mrow + l15) * K + quad * 8;
    const u16* Bp = Bt + (size_t)(col0 + l15) * K + quad * 8;

    f4_t acc[2][4];
    #pragma unroll
    for (int mi = 0; mi < 2; ++mi)
        #pragma unroll
        for (int ni = 0; ni < 4; ++ni)
            acc[mi][ni] = (f4_t){0.f, 0.f, 0.f, 0.f};

    for (int k0 = 0; k0 < K; k0 += 64) {
        bf8_t a[2][2], bb[4][2];
        #pragma unroll
        for (int kc = 0; kc < 2; ++kc) {
            #pragma unroll
            for (int mi = 0; mi < 2; ++mi)
                a[mi][kc] = *(const bf8_t*)(Ap + (size_t)mi * 16 * K + k0 + kc * 32);
            #pragma unroll
            for (int ni = 0; ni < 4; ++ni)
                bb[ni][kc] = *(const bf8_t*)(Bp + (size_t)ni * 16 * K + k0 + kc * 32);
        }
        #pragma unroll
        for (int kc = 0; kc < 2; ++kc)
            #pragma unroll
            for (int ni = 0; ni < 4; ++ni)
                #pragma unroll
                for (int mi = 0; mi < 2; ++mi)
                    acc[mi][ni] = __builtin_amdgcn_mfma_f32_16x16x32_bf16(
                        a[mi][kc], bb[ni][kc], acc[mi][ni], 0, 0, 0);
    }

    float bz[4];
    #pragma unroll
    for (int ni = 0; ni < 4; ++ni) bz[ni] = bf2f(bias[col0 + ni * 16 + l15]);
    #pragma unroll
    for (int mi = 0; mi < 2; ++mi)
        #pragma unroll
        for (int r = 0; r < 4; ++r) {
            int rg = mrow + mi * 16 + quad * 4 + r;
            size_t base = (size_t)rg * N + col0 + l15;
            if (MODE == EP_MERGE) {          // + bm + x (bf16) -> f32 x2
                const u16* R = (const u16*)res;
                #pragma unroll
                for (int ni = 0; ni < 4; ++ni)
                    ((float*)outp)[base + ni * 16] =
                        acc[mi][ni][r] + bz[ni] + bf2f(R[base + ni * 16]);
            } else {                          // EP_FFN2: + x2 (f32) -> fp32 d_out
                const float* R = (const float*)res;
                #pragma unroll
                for (int ni = 0; ni < 4; ++ni)
                    ((float*)outp)[base + ni * 16] =
                        acc[mi][ni][r] + bz[ni] + R[base + ni * 16];
            }
        }
}

// ---------------- MFMA flash attention, single-pass, norm-bound max, S^T form ----------------
// NOTE: plain launch_bounds(256). R12's (256,4) capped VGPR at 64 -> accumulator
// spill to scratch (WRITE_SIZE 32KB -> 166MB) and +19us. Never cap below acc footprint.
__global__ __launch_bounds__(256) void attn_k(
    const u16* __restrict__ qh, const u16* __restrict__ kh,
    const u16* __restrict__ vhT, const float* __restrict__ maxk,
    u16* __restrict__ ao)
{
    const int t = threadIdx.x;
    const int w = t >> 6, lane = t & 63;
    const int l15 = lane & 15, quad = lane >> 4;
    const int id = blockIdx.x;
    const int qt = (id >> 3) & 31;
    const int bh = (id >> 8) * 8 + (id & 7);   // id%8 = XCD affinity per (b,h)
    const int b  = bh >> 3, h = bh & 7;
    const int n0 = qt * 64;
    const float SCALE = 0.17677669529663687f;  // 1/sqrt(32)

    const u16* Q  = qh  + (size_t)bh * 2048 * 32;
    const u16* Kp = kh  + (size_t)bh * 2048 * 32;
    const u16* Vt = vhT + (size_t)bh * 256 * 2048;   // [vchan][key]

    __shared__ __align__(16) u16 Pb[2][64][136];     // [buf][q row][key 0..127 +pad]
    __shared__ __align__(16) float lds_l[64];

    const bf8_t qf = *(const bf8_t*)(Q + (size_t)(n0 + 16 * w + l15) * 32 + quad * 8);
    const f4_t zf = {0.f, 0.f, 0.f, 0.f};

    float q2 = 0.f;
    #pragma unroll
    for (int i = 0; i < 8; ++i) { float qv = bf2f((u16)qf[i]); q2 += qv * qv; }
    q2 += __shfl_xor(q2, 16, 64);
    q2 += __shfl_xor(q2, 32, 64);
    const float mrow = SCALE * sqrtf(q2) * maxk[bh];

    f4_t acc[4][4];
    #pragma unroll
    for (int i = 0; i < 4; ++i)
        #pragma unroll
        for (int j = 0; j < 4; ++j)
            acc[i][j] = (f4_t){0.f, 0.f, 0.f, 0.f};
    float lsum = 0.f;

    int bufi = 0;
    for (int kt = 0; kt < 2048; kt += 128, bufi ^= 1) {
        #pragma unroll
        for (int jt = 0; jt < 8; ++jt) {
            bf8_t kf = *(const bf8_t*)(Kp + (size_t)(kt + jt * 16 + l15) * 32 + quad * 8);
            f4_t s = __builtin_amdgcn_mfma_f32_16x16x32_bf16(kf, qf, zf, 0, 0, 0);
            float p0 = __expf(fmaf(s[0], SCALE, -mrow));
            float p1 = __expf(fmaf(s[1], SCALE, -mrow));
            float p2 = __expf(fmaf(s[2], SCALE, -mrow));
            float p3 = __expf(fmaf(s[3], SCALE, -mrow));
            lsum += (p0 + p1) + (p2 + p3);
            ushort4 pk;
            pk.x = f2bf(p0); pk.y = f2bf(p1); pk.z = f2bf(p2); pk.w = f2bf(p3);
            *(ushort4*)&Pb[bufi][16 * w + l15][jt * 16 + quad * 4] = pk;
        }
        __syncthreads();
        #pragma unroll
        for (int kc = 0; kc < 4; ++kc) {
            bf8_t af[4];
            #pragma unroll
            for (int mt = 0; mt < 4; ++mt)
                af[mt] = *(const bf8_t*)&Pb[bufi][mt * 16 + l15][kc * 32 + quad * 8];
            #pragma unroll
            for (int nt = 0; nt < 4; ++nt) {
                bf8_t vf = *(const bf8_t*)(Vt + (size_t)(64 * w + nt * 16 + l15) * 2048
                                           + kt + kc * 32 + quad * 8);
                #pragma unroll
                for (int mt = 0; mt < 4; ++mt)
                    acc[mt][nt] = __builtin_amdgcn_mfma_f32_16x16x32_bf16(
                        af[mt], vf, acc[mt][nt], 0, 0, 0);
            }
        }
    }

    lsum += __shfl_xor(lsum, 16, 64);
    lsum += __shfl_xor(lsum, 32, 64);
    if (lane < 16) lds_l[16 * w + l15] = lsum;
    __syncthreads();
    #pragma unroll
    for (int mt = 0; mt < 4; ++mt) {
        f4_t lv = *(const f4_t*)&lds_l[mt * 16 + quad * 4];
        #pragma unroll
        for (int r = 0; r < 4; ++r) {
            float inv = 1.0f / lv[r];
            size_t rowbase = ((size_t)(b * 2048 + n0 + mt * 16 + quad * 4 + r)) * 2048
                             + h * 256 + 64 * w;
            #pragma unroll
            for (int nt = 0; nt < 4; ++nt)
                ao[rowbase + nt * 16 + l15] = f2bf(acc[mt][nt][r] * inv);
        }
    }
}

extern "C" void kernel_launch(void* const* d_in, const int* in_sizes, int n_in,
                              void* d_out, int out_size, void* d_ws, size_t ws_size,
                              hipStream_t stream)
{
    u16* wsu = (u16*)d_ws;
    int* flag = (int*)d_ws;
    float* mk = (float*)(wsu + 64);              // 32 f32

    // workspace layout (u16 units), ~95.7 MB (known-safe)
    const size_t CVT0 = 128;
    const size_t Y0   = CVT0 + SEG_TOT;          // y bf16 [8192,256]
    const size_t QH0  = Y0  + 2097152;
    const size_t KH0  = QH0 + 2097152;
    const size_t VT0  = KH0 + 2097152;           // vhT bf16 [B*H*256][2048]
    const size_t AO0  = VT0 + 16777216;          // ao bf16 [8192][2048]
    const size_t X20  = AO0 + 16777216;          // x2 f32 [8192,256]
    // hbb bf16 [8192,1024] aliases AO0 (ao dead after merge GEMM)

    u16* cvt = wsu + CVT0;
    u16* y   = wsu + Y0;
    u16* qh  = wsu + QH0;
    u16* kh  = wsu + KH0;
    u16* vhT = wsu + VT0;
    u16* ao  = wsu + AO0;
    float* x2 = (float*)(wsu + X20);
    u16* hbb  = wsu + AO0;

    const u16* xc   = cvt + SEG_X;
    const u16* ln1g = cvt + SEG_LN1G;
    const u16* ln1b = cvt + SEG_LN1B;
    const u16* Wqkv = cvt + SEG_WQKV;   // transposed [2560][256]
    const u16* bqkv = cvt + SEG_BQKV;
    const u16* Wm   = cvt + SEG_WM;     // transposed [256][2048]
    const u16* bm   = cvt + SEG_BM;
    const u16* ln2g = cvt + SEG_LN2G;
    const u16* ln2b = cvt + SEG_LN2B;
    const u16* W1   = cvt + SEG_W1;     // transposed [1024][256]
    const u16* b1   = cvt + SEG_B1;
    const u16* W2   = cvt + SEG_W2;     // transposed [256][1024]
    const u16* b2   = cvt + SEG_B2;

    sniff_k<<<1, 256, 0, stream>>>((const u16*)d_in[0], flag);
    conv_k<<<SEG_TOT / 256, 256, 0, stream>>>(
        d_in[0], d_in[1], d_in[2], d_in[3], d_in[4], d_in[5], d_in[6],
        d_in[7], d_in[8], d_in[9], d_in[10], d_in[11], d_in[12], flag, cvt);

    ln_k<true><<<ROWS / 4, 256, 0, stream>>>(xc, ln1g, ln1b, y);
    gemm_big<EP_QKV><<<dim3(2560 / 64, ROWS / 256), 256, 0, stream>>>(
        y, Wqkv, bqkv, nullptr, qh, kh, vhT, 2560, 256);
    maxk_k<<<32, 256, 0, stream>>>(kh, mk);
    attn_k<<<1024, 256, 0, stream>>>(qh, kh, vhT, mk, ao);
    gemm_mfma<EP_MERGE><<<dim3(256 / 64, ROWS / 128), 256, 0, stream>>>(
        ao, Wm, bm, xc, x2, 256, 2048);
    ln_k<false><<<ROWS / 4, 256, 0, stream>>>(x2, ln2g, ln2b, y);
    gemm_big<EP_GELU><<<dim3(1024 / 64, ROWS / 256), 256, 0, stream>>>(
        y, W1, b1, hbb, nullptr, nullptr, nullptr, 1024, 256);
    gemm_mfma<EP_FFN2><<<dim3(256 / 64, ROWS / 128), 256, 0, stream>>>(
        hbb, W2, b2, x2, d_out, 256, 1024);
}